// Round 3
// baseline (509.501 us; speedup 1.0000x reference)
//
#include <hip/hip_runtime.h>
#include <hip/hip_bf16.h>

#define NTOK 16384
#define HD   4096
#define NE   64

// PRE path: 16 tokens/block, 1024 blocks -> 4 blocks/CU -> 4 waves/SIMD
#define TPRE     16
#define NBLK_PRE (NTOK / TPRE)
#define KSTEPS   (HD / 32)     // 128 k-steps of 32

// FB path (round-0 verified): 32 tokens/block
#define TFB      32
#define NBLK_FB  (NTOK / TFB)
#define NIT      (HD / 32)

// LDS strides (elements)
#define SAB 40   // fb: bf16 32 K + 8 pad
#define SL  68   // float stride for logits tiles

// ws layout (floats): [0,64)=P_sum, [64,128)=counts, [128]=z_sum, pad to 192,
// then Bhi (bf16, NE*HD), then Blo (bf16, NE*HD). ~1.05 MB total.
#define WS_ACC_FLOATS 192
#define B_ELEMS (NE * HD)

typedef __bf16 bf16x8 __attribute__((ext_vector_type(8)));
typedef __bf16 bf16x4 __attribute__((ext_vector_type(4)));
typedef float  f32x4  __attribute__((ext_vector_type(4)));

__device__ __forceinline__ f32x4 mfma16(bf16x8 a, bf16x8 b, f32x4 c) {
    return __builtin_amdgcn_mfma_f32_16x16x32_bf16(a, b, c, 0, 0, 0);
}

__device__ __forceinline__ void cvt_split(float4 v, bf16x4& hi, bf16x4& lo) {
    float x[4] = {v.x, v.y, v.z, v.w};
    #pragma unroll
    for (int e = 0; e < 4; ++e) {
        __bf16 h = (__bf16)x[e];        // RNE
        hi[e] = h;
        lo[e] = (__bf16)(x[e] - (float)h);
    }
}

__device__ __forceinline__ void cvt8(float4 x0, float4 x1, bf16x8& hi, bf16x8& lo) {
    bf16x4 h, l;
    cvt_split(x0, h, l);
    #pragma unroll
    for (int e = 0; e < 4; ++e) { hi[e] = h[e]; lo[e] = l[e]; }
    cvt_split(x1, h, l);
    #pragma unroll
    for (int e = 0; e < 4; ++e) { hi[4 + e] = h[e]; lo[4 + e] = l[e]; }
}

__global__ void zero_ws_kernel(float* ws) {
    int i = threadIdx.x;
    if (i < 129) ws[i] = 0.0f;
}

// One-shot: zero accumulators + convert W_gate fp32 -> bf16 hi/lo in ws.
__global__ __launch_bounds__(256) void prep_kernel(
    const float* __restrict__ Wg, float* __restrict__ ws)
{
    const int tid = threadIdx.x;
    if (blockIdx.x == 0 && tid < 129) ws[tid] = 0.0f;
    __bf16* Bhi = (__bf16*)(ws + WS_ACC_FLOATS);
    __bf16* Blo = Bhi + B_ELEMS;
    const int i = (blockIdx.x * 256 + tid) * 8;
    float4 v0 = *(const float4*)(Wg + i);
    float4 v1 = *(const float4*)(Wg + i + 4);
    bf16x4 h0, l0, h1, l1;
    cvt_split(v0, h0, l0);
    cvt_split(v1, h1, l1);
    *(bf16x4*)(Bhi + i)     = h0;
    *(bf16x4*)(Bhi + i + 4) = h1;
    *(bf16x4*)(Blo + i)     = l0;
    *(bf16x4*)(Blo + i + 4) = l1;
}

// PRE router: barrier-free k-loop, per-wave independent 16x16 output tile,
// 4-slot depth-3 register pipeline for both A (global fp32) and B (pre-split
// bf16 hi/lo, L2-resident). No LDS in the GEMM; LDS only for the epilogue.
__global__ __launch_bounds__(256, 4) void router_pre_kernel(
    const float* __restrict__ hs,
    const __bf16* __restrict__ Bhi,
    const __bf16* __restrict__ Blo,
    float* __restrict__ out,
    float* __restrict__ ws)
{
    __shared__ float sLog[TPRE * SL];   // 4,352 B
    __shared__ float sInv[TPRE];
    __shared__ float sPp[4 * 64];
    __shared__ float sCnt[64];
    __shared__ float sZ;

    const int tid = threadIdx.x;
    const int t0  = blockIdx.x * TPRE;

    if (tid < 64) sCnt[tid] = 0.0f;
    if (tid == 0) sZ = 0.0f;

    const int lane = tid & 63;
    const int wv   = tid >> 6;      // 0..3 -> expert group (wv*16)
    const int fm   = lane & 15;
    const int fq   = lane >> 4;     // 0..3
    const int fk   = fq * 8;        // k offset within 32-step

    // Per-lane base pointers
    const float*  pA  = hs  + (size_t)(t0 + fm) * HD + fk;
    const __bf16* pBh = Bhi + (size_t)(wv * 16 + fm) * HD + fk;
    const __bf16* pBl = Blo + (size_t)(wv * 16 + fm) * HD + fk;

    f32x4 acc = (f32x4){0.f, 0.f, 0.f, 0.f};

    // 4-slot register pipeline (all indices compile-time constant)
    float4 fa0[4], fa1[4];
    bf16x8 fbh[4], fbl[4];

    #pragma unroll
    for (int i = 0; i < 4; ++i) {
        fa0[i] = *(const float4*)(pA + i * 32);
        fa1[i] = *(const float4*)(pA + i * 32 + 4);
        fbh[i] = *(const bf16x8*)(pBh + i * 32);
        fbl[i] = *(const bf16x8*)(pBl + i * 32);
    }

    // STEP(i): compute slot i (k-step kb+i), then reload slot i for k-step kb+i+4.
    // Issue->use distance = 3 step bodies; x4 waves/SIMD covers HBM latency.
#define STEP_LOAD(i, kb)                                                 \
    {                                                                    \
        bf16x8 ahi, alo;                                                 \
        cvt8(fa0[i], fa1[i], ahi, alo);                                  \
        acc = mfma16(ahi, fbh[i], acc);                                  \
        acc = mfma16(ahi, fbl[i], acc);                                  \
        acc = mfma16(alo, fbh[i], acc);                                  \
        acc = mfma16(alo, fbl[i], acc);                                  \
        const int nks = (kb) + (i) + 4;                                  \
        fa0[i] = *(const float4*)(pA + nks * 32);                        \
        fa1[i] = *(const float4*)(pA + nks * 32 + 4);                    \
        fbh[i] = *(const bf16x8*)(pBh + nks * 32);                       \
        fbl[i] = *(const bf16x8*)(pBl + nks * 32);                       \
    }
#define STEP_NOLOAD(i)                                                   \
    {                                                                    \
        bf16x8 ahi, alo;                                                 \
        cvt8(fa0[i], fa1[i], ahi, alo);                                  \
        acc = mfma16(ahi, fbh[i], acc);                                  \
        acc = mfma16(ahi, fbl[i], acc);                                  \
        acc = mfma16(alo, fbh[i], acc);                                  \
        acc = mfma16(alo, fbl[i], acc);                                  \
    }

    for (int it = 0; it < (KSTEPS / 4) - 1; ++it) {   // 31 macro-iters
        const int kb = it * 4;
        STEP_LOAD(0, kb)
        STEP_LOAD(1, kb)
        STEP_LOAD(2, kb)
        STEP_LOAD(3, kb)
    }
    STEP_NOLOAD(0)   // k-steps 124..127
    STEP_NOLOAD(1)
    STEP_NOLOAD(2)
    STEP_NOLOAD(3)
#undef STEP_LOAD
#undef STEP_NOLOAD

    // ---- scatter logits: C/D layout col=lane&15 (expert), row=fq*4+reg (token)
    #pragma unroll
    for (int r = 0; r < 4; ++r) {
        const int tokl = fq * 4 + r;          // 0..15
        const int expl = wv * 16 + fm;        // 0..63
        sLog[tokl * SL + expl] = acc[r];
    }
    __syncthreads();

    // ---- softmax/top-2: 16 lanes per token, 4 experts per lane
    const int g = tid >> 4;       // token 0..15
    const int l = tid & 15;
    float* Lrow = &sLog[g * SL + l * 4];
    float lv[4];
    float m = -3.0e38f;
    #pragma unroll
    for (int c = 0; c < 4; ++c) { lv[c] = Lrow[c]; m = fmaxf(m, lv[c]); }
    m = fmaxf(m, __shfl_xor(m, 1, 64));
    m = fmaxf(m, __shfl_xor(m, 2, 64));
    m = fmaxf(m, __shfl_xor(m, 4, 64));
    m = fmaxf(m, __shfl_xor(m, 8, 64));

    float v1 = -3.0e38f, v2 = -3.0e38f; int i1 = 0, i2 = 0;
    float ssum = 0.0f;
    #pragma unroll
    for (int c = 0; c < 4; ++c) {
        const float val = lv[c]; const int idx = l * 4 + c;
        const float ev = __expf(val - m);
        Lrow[c] = ev;               // overwrite logits with exp(l - m)
        ssum += ev;
        if (val > v1) { v2 = v1; i2 = i1; v1 = val; i1 = idx; }
        else if (val > v2) { v2 = val; i2 = idx; }
    }
    ssum += __shfl_xor(ssum, 1, 64);
    ssum += __shfl_xor(ssum, 2, 64);
    ssum += __shfl_xor(ssum, 4, 64);
    ssum += __shfl_xor(ssum, 8, 64);

    #pragma unroll
    for (int s = 1; s <= 8; s <<= 1) {
        const float ov1 = __shfl_xor(v1, s, 64);
        const int   oi1 = __shfl_xor(i1, s, 64);
        const float ov2 = __shfl_xor(v2, s, 64);
        const int   oi2 = __shfl_xor(i2, s, 64);
        float n1, n2; int ni1, ni2;
        const bool ofirst = (ov1 > v1) || (ov1 == v1 && oi1 < i1);
        if (ofirst) {
            n1 = ov1; ni1 = oi1;
            const bool osec = (ov2 > v1) || (ov2 == v1 && oi2 < i1);
            n2 = osec ? ov2 : v1; ni2 = osec ? oi2 : i1;
        } else {
            n1 = v1; ni1 = i1;
            const bool asec = (v2 > ov1) || (v2 == ov1 && i2 < oi1);
            n2 = asec ? v2 : ov1; ni2 = asec ? i2 : oi1;
        }
        v1 = n1; i1 = ni1; v2 = n2; i2 = ni2;
    }

    if (l == 0) {
        const float e1 = __expf(v1 - m), e2 = __expf(v2 - m);
        const float winv = 1.0f / (e1 + e2);
        const int token = t0 + g;
        out[2 * token]     = e1 * winv;
        out[2 * token + 1] = e2 * winv;
        out[2 * NTOK + 2 * token]     = (float)i1;   // indices as f32 (concat promotion)
        out[2 * NTOK + 2 * token + 1] = (float)i2;
        const float lse = m + __logf(ssum);
        atomicAdd(&sZ, lse * lse);
        atomicAdd(&sCnt[i1], 1.0f);
        atomicAdd(&sCnt[i2], 1.0f);
        sInv[g] = 1.0f / ssum;
    }
    __syncthreads();

    // ---- block-local P sums over 16 tokens, then global atomics
    {
        const int e = tid & 63;
        const int q = tid >> 6;     // 0..3
        float part = 0.0f;
        #pragma unroll
        for (int t = 0; t < 4; ++t) {
            const int tok = q * 4 + t;
            part += sLog[tok * SL + e] * sInv[tok];
        }
        sPp[q * 64 + e] = part;
    }
    __syncthreads();
    if (tid < 64) {
        const float ps = sPp[tid] + sPp[64 + tid] + sPp[128 + tid] + sPp[192 + tid];
        atomicAdd(&ws[tid], ps);             // sum of probs per expert
        atomicAdd(&ws[64 + tid], sCnt[tid]); // top-2 counts per expert
    }
    if (tid == 0) atomicAdd(&ws[128], sZ);
}

// Fallback (ws too small for B copies): round-0 verified kernel.
__global__ __launch_bounds__(256) void router_fb_kernel(
    const float* __restrict__ hs,
    const float* __restrict__ Wg,
    float* __restrict__ out,
    float* __restrict__ ws)
{
    __shared__ __bf16 sAhi[2][TFB * SAB];
    __shared__ __bf16 sAlo[2][TFB * SAB];
    __shared__ __bf16 sBhi[2][NE * SAB];
    __shared__ __bf16 sBlo[2][NE * SAB];
    __shared__ float  sLog[TFB * SL];
    __shared__ float  sInv[TFB];
    __shared__ float  sPp[4 * 64];
    __shared__ float  sCnt[64];
    __shared__ float  sZ;

    const int tid = threadIdx.x;
    const int t0  = blockIdx.x * TFB;

    if (tid < 64) sCnt[tid] = 0.0f;
    if (tid == 0) sZ = 0.0f;

    const int r1 = tid >> 3;
    const int c4 = (tid & 7) * 4;
    const float* gA = hs + (size_t)(t0 + r1) * HD + c4;
    const float* gB = Wg + (size_t)r1 * HD + c4;
    const int oA  = r1 * SAB + c4;
    const int oB1 = r1 * SAB + c4;
    const int oB2 = (r1 + 32) * SAB + c4;

    const int lane = tid & 63;
    const int wv   = tid >> 6;
    const int wr   = (wv >> 1) * 16;
    const int wc   = (wv & 1) * 32;
    const int fm   = lane & 15;
    const int fq   = lane >> 4;
    const int fk   = fq * 8;

    f32x4 acc[2];
    acc[0] = (f32x4){0.f, 0.f, 0.f, 0.f};
    acc[1] = (f32x4){0.f, 0.f, 0.f, 0.f};

    {
        float4 a0 = *(const float4*)(gA);
        float4 b0 = *(const float4*)(gB);
        float4 b1 = *(const float4*)(gB + 32 * HD);
        bf16x4 h, l;
        cvt_split(a0, h, l); *(bf16x4*)&sAhi[0][oA]  = h; *(bf16x4*)&sAlo[0][oA]  = l;
        cvt_split(b0, h, l); *(bf16x4*)&sBhi[0][oB1] = h; *(bf16x4*)&sBlo[0][oB1] = l;
        cvt_split(b1, h, l); *(bf16x4*)&sBhi[0][oB2] = h; *(bf16x4*)&sBlo[0][oB2] = l;
    }
    __syncthreads();

    for (int it = 0; it < NIT; ++it) {
        const int cur = it & 1;
        const bool more = (it + 1) < NIT;
        float4 na0, nb0, nb1;
        if (more) {
            const int k0 = (it + 1) * 32;
            na0 = *(const float4*)(gA + k0);
            nb0 = *(const float4*)(gB + k0);
            nb1 = *(const float4*)(gB + 32 * HD + k0);
        }

        bf16x8 ahi, alo, bhi[2], blo[2];
        {
            const int aoff = (wr + fm) * SAB + fk;
            ahi = *(const bf16x8*)&sAhi[cur][aoff];
            alo = *(const bf16x8*)&sAlo[cur][aoff];
        }
        #pragma unroll
        for (int j = 0; j < 2; ++j) {
            const int boff = (wc + j * 16 + fm) * SAB + fk;
            bhi[j] = *(const bf16x8*)&sBhi[cur][boff];
            blo[j] = *(const bf16x8*)&sBlo[cur][boff];
        }
        #pragma unroll
        for (int j = 0; j < 2; ++j) {
            acc[j] = mfma16(ahi, bhi[j], acc[j]);
            acc[j] = mfma16(ahi, blo[j], acc[j]);
            acc[j] = mfma16(alo, bhi[j], acc[j]);
            acc[j] = mfma16(alo, blo[j], acc[j]);
        }

        if (more) {
            const int nb = cur ^ 1;
            bf16x4 h, l;
            cvt_split(na0, h, l); *(bf16x4*)&sAhi[nb][oA]  = h; *(bf16x4*)&sAlo[nb][oA]  = l;
            cvt_split(nb0, h, l); *(bf16x4*)&sBhi[nb][oB1] = h; *(bf16x4*)&sBlo[nb][oB1] = l;
            cvt_split(nb1, h, l); *(bf16x4*)&sBhi[nb][oB2] = h; *(bf16x4*)&sBlo[nb][oB2] = l;
        }
        __syncthreads();
    }

    #pragma unroll
    for (int j = 0; j < 2; ++j)
        #pragma unroll
        for (int r = 0; r < 4; ++r) {
            const int tokl = wr + fq * 4 + r;
            const int expl = wc + j * 16 + fm;
            sLog[tokl * SL + expl] = acc[j][r];
        }
    __syncthreads();

    const int g = tid >> 3;
    const int l = tid & 7;
    float* Lrow = &sLog[g * SL + l * 8];
    float lv[8];
    float m = -3.0e38f;
    #pragma unroll
    for (int c = 0; c < 8; ++c) { lv[c] = Lrow[c]; m = fmaxf(m, lv[c]); }
    m = fmaxf(m, __shfl_xor(m, 1, 64));
    m = fmaxf(m, __shfl_xor(m, 2, 64));
    m = fmaxf(m, __shfl_xor(m, 4, 64));

    float v1 = -3.0e38f, v2 = -3.0e38f; int i1 = 0, i2 = 0;
    float ssum = 0.0f;
    #pragma unroll
    for (int c = 0; c < 8; ++c) {
        const float val = lv[c]; const int idx = l * 8 + c;
        const float ev = __expf(val - m);
        Lrow[c] = ev;
        ssum += ev;
        if (val > v1) { v2 = v1; i2 = i1; v1 = val; i1 = idx; }
        else if (val > v2) { v2 = val; i2 = idx; }
    }
    ssum += __shfl_xor(ssum, 1, 64);
    ssum += __shfl_xor(ssum, 2, 64);
    ssum += __shfl_xor(ssum, 4, 64);

    #pragma unroll
    for (int s = 1; s <= 4; s <<= 1) {
        const float ov1 = __shfl_xor(v1, s, 64);
        const int   oi1 = __shfl_xor(i1, s, 64);
        const float ov2 = __shfl_xor(v2, s, 64);
        const int   oi2 = __shfl_xor(i2, s, 64);
        float n1, n2; int ni1, ni2;
        const bool ofirst = (ov1 > v1) || (ov1 == v1 && oi1 < i1);
        if (ofirst) {
            n1 = ov1; ni1 = oi1;
            const bool osec = (ov2 > v1) || (ov2 == v1 && oi2 < i1);
            n2 = osec ? ov2 : v1; ni2 = osec ? oi2 : i1;
        } else {
            n1 = v1; ni1 = i1;
            const bool asec = (v2 > ov1) || (v2 == ov1 && i2 < oi1);
            n2 = asec ? v2 : ov1; ni2 = asec ? i2 : oi1;
        }
        v1 = n1; i1 = ni1; v2 = n2; i2 = ni2;
    }

    if (l == 0) {
        const float e1 = __expf(v1 - m), e2 = __expf(v2 - m);
        const float winv = 1.0f / (e1 + e2);
        const int token = t0 + g;
        out[2 * token]     = e1 * winv;
        out[2 * token + 1] = e2 * winv;
        out[2 * NTOK + 2 * token]     = (float)i1;
        out[2 * NTOK + 2 * token + 1] = (float)i2;
        const float lse = m + __logf(ssum);
        atomicAdd(&sZ, lse * lse);
        atomicAdd(&sCnt[i1], 1.0f);
        atomicAdd(&sCnt[i2], 1.0f);
        sInv[g] = 1.0f / ssum;
    }
    __syncthreads();

    {
        const int e = tid & 63;
        const int q = tid >> 6;
        float part = 0.0f;
        #pragma unroll
        for (int t = 0; t < 8; ++t) {
            const int tok = q * 8 + t;
            part += sLog[tok * SL + e] * sInv[tok];
        }
        sPp[q * 64 + e] = part;
    }
    __syncthreads();
    if (tid < 64) {
        const float ps = sPp[tid] + sPp[64 + tid] + sPp[128 + tid] + sPp[192 + tid];
        atomicAdd(&ws[tid], ps);
        atomicAdd(&ws[64 + tid], sCnt[tid]);
    }
    if (tid == 0) atomicAdd(&ws[128], sZ);
}

__global__ void finalize_kernel(const float* __restrict__ ws, float* __restrict__ out) {
    const int e = threadIdx.x;   // 64 threads, one wave
    const float P = ws[e] * (1.0f / NTOK);
    const float f = ws[64 + e] * (1.0f / (NTOK * 2));
    float term = f * P;
    #pragma unroll
    for (int s = 32; s >= 1; s >>= 1) term += __shfl_xor(term, s, 64);
    if (e == 0) {
        const float lb = 64.0f * term;
        const float z  = ws[128] * (1.0f / NTOK);
        out[4 * NTOK] = 0.001f * lb + 0.001f * z;
    }
}

extern "C" void kernel_launch(void* const* d_in, const int* in_sizes, int n_in,
                              void* d_out, int out_size, void* d_ws, size_t ws_size,
                              hipStream_t stream) {
    const float* hs = (const float*)d_in[0];
    const float* Wg = (const float*)d_in[1];
    float* out = (float*)d_out;
    float* ws  = (float*)d_ws;

    const size_t need = (size_t)WS_ACC_FLOATS * sizeof(float)
                      + (size_t)B_ELEMS * 2 * sizeof(__bf16);
    if (ws_size >= need) {
        const __bf16* Bhi = (const __bf16*)(ws + WS_ACC_FLOATS);
        const __bf16* Blo = Bhi + B_ELEMS;
        hipLaunchKernelGGL(prep_kernel, dim3(128), dim3(256), 0, stream, Wg, ws);
        hipLaunchKernelGGL(router_pre_kernel, dim3(NBLK_PRE), dim3(256), 0, stream,
                           hs, Bhi, Blo, out, ws);
    } else {
        hipLaunchKernelGGL(zero_ws_kernel, dim3(1), dim3(256), 0, stream, ws);
        hipLaunchKernelGGL(router_fb_kernel, dim3(NBLK_FB), dim3(256), 0, stream,
                           hs, Wg, out, ws);
    }
    hipLaunchKernelGGL(finalize_kernel, dim3(1), dim3(64), 0, stream, ws, out);
}

// Round 4
// 458.124 us; speedup vs baseline: 1.1121x; 1.1121x over previous
//
#include <hip/hip_runtime.h>
#include <hip/hip_bf16.h>

#define NTOK 16384
#define HD   4096
#define NE   64

// PRE path: 16 tokens/block, 1024 blocks -> 4 blocks/CU, ~31 KB LDS/block
#define TPRE     16
#define NBLK_PRE (NTOK / TPRE)
#define NITP     (HD / 32)     // 128 k-tiles of 32

// FB path (round-0 verified): 32 tokens/block
#define TFB      32
#define NBLK_FB  (NTOK / TFB)
#define NIT      (HD / 32)

// LDS strides (elements)
#define SAB 40   // bf16: 32 K-elems + 8 pad -> 80 B rows (2-way bank conflict max)
#define SL  68   // float stride for logits tiles

// ws layout (floats): [0,64)=P_sum, [64,128)=counts, [128]=z_sum, pad to 192,
// then Bhi (bf16, NE*HD), then Blo (bf16, NE*HD). ~1.05 MB total.
#define WS_ACC_FLOATS 192
#define B_ELEMS (NE * HD)

typedef __bf16 bf16x8 __attribute__((ext_vector_type(8)));
typedef __bf16 bf16x4 __attribute__((ext_vector_type(4)));
typedef float  f32x4  __attribute__((ext_vector_type(4)));

__device__ __forceinline__ f32x4 mfma16(bf16x8 a, bf16x8 b, f32x4 c) {
    return __builtin_amdgcn_mfma_f32_16x16x32_bf16(a, b, c, 0, 0, 0);
}

__device__ __forceinline__ void cvt_split(float4 v, bf16x4& hi, bf16x4& lo) {
    float x[4] = {v.x, v.y, v.z, v.w};
    #pragma unroll
    for (int e = 0; e < 4; ++e) {
        __bf16 h = (__bf16)x[e];        // RNE
        hi[e] = h;
        lo[e] = (__bf16)(x[e] - (float)h);
    }
}

__global__ void zero_ws_kernel(float* ws) {
    int i = threadIdx.x;
    if (i < 129) ws[i] = 0.0f;
}

// One-shot: zero accumulators + convert W_gate fp32 -> bf16 hi/lo in ws.
__global__ __launch_bounds__(256) void prep_kernel(
    const float* __restrict__ Wg, float* __restrict__ ws)
{
    const int tid = threadIdx.x;
    if (blockIdx.x == 0 && tid < 129) ws[tid] = 0.0f;
    __bf16* Bhi = (__bf16*)(ws + WS_ACC_FLOATS);
    __bf16* Blo = Bhi + B_ELEMS;
    const int i = (blockIdx.x * 256 + tid) * 8;
    float4 v0 = *(const float4*)(Wg + i);
    float4 v1 = *(const float4*)(Wg + i + 4);
    bf16x4 h0, l0, h1, l1;
    cvt_split(v0, h0, l0);
    cvt_split(v1, h1, l1);
    *(bf16x4*)(Bhi + i)     = h0;
    *(bf16x4*)(Bhi + i + 4) = h1;
    *(bf16x4*)(Blo + i)     = l0;
    *(bf16x4*)(Blo + i + 4) = l1;
}

// PRE router: round-0 proven barriered LDS double-buffer structure, scaled to
// 16 tokens/block (1024 blocks -> 4 blocks/CU for latency hiding) and with B
// staged as a pure bf16 copy from the pre-split arrays (no in-loop conversion).
// Only A pays a cvt_split, on half the threads.
__global__ __launch_bounds__(256) void router_pre_kernel(
    const float* __restrict__ hs,
    const __bf16* __restrict__ Bhi,
    const __bf16* __restrict__ Blo,
    float* __restrict__ out,
    float* __restrict__ ws)
{
    __shared__ __bf16 sAhi[2][TPRE * SAB];   // 2,560 B
    __shared__ __bf16 sAlo[2][TPRE * SAB];   // 2,560 B
    __shared__ __bf16 sBhi[2][NE * SAB];     // 10,240 B
    __shared__ __bf16 sBlo[2][NE * SAB];     // 10,240 B
    __shared__ float  sLog[TPRE * SL];       // 4,352 B
    __shared__ float  sInv[TPRE];
    __shared__ float  sPp[4 * 64];
    __shared__ float  sCnt[64];
    __shared__ float  sZ;
    // total ~31 KB -> 4 blocks/CU co-resident at grid 1024

    const int tid = threadIdx.x;
    const int t0  = blockIdx.x * TPRE;

    if (tid < 64) sCnt[tid] = 0.0f;
    if (tid == 0) sZ = 0.0f;

    // ---- A staging (threads 0..127): 1 float4 of A per iter
    const int ra = tid >> 3;            // 0..31 (only 0..15 used)
    const int c4 = (tid & 7) * 4;       // k offset (floats)
    const bool doA = (tid < 128);
    const float* gA = hs + (size_t)(t0 + (ra & 15)) * HD + c4;
    const int oA = (ra & 15) * SAB + c4;

    // ---- B staging (all 256 threads): copy 16 B of Bhi + 16 B of Blo per iter
    const int eb = tid >> 2;            // expert 0..63
    const int kc = (tid & 3) * 8;       // k offset (bf16 elems)
    const __bf16* gBh = Bhi + (size_t)eb * HD + kc;
    const __bf16* gBl = Blo + (size_t)eb * HD + kc;
    const int oB = eb * SAB + kc;

    // ---- wave tile: 16 tok x 16 exp per wave; 4 waves cover 16x64
    const int lane = tid & 63;
    const int wv   = tid >> 6;      // expert group wv*16
    const int fm   = lane & 15;
    const int fq   = lane >> 4;     // 0..3
    const int fk   = fq * 8;        // k offset within 32-tile

    const int aoff = fm * SAB + fk;
    const int boff = (wv * 16 + fm) * SAB + fk;

    f32x4 acc = (f32x4){0.f, 0.f, 0.f, 0.f};

    // ---- prologue: stage k-tile 0 into buffer 0
    {
        if (doA) {
            float4 a0 = *(const float4*)(gA);
            bf16x4 h, l;
            cvt_split(a0, h, l);
            *(bf16x4*)&sAhi[0][oA] = h;
            *(bf16x4*)&sAlo[0][oA] = l;
        }
        *(bf16x8*)&sBhi[0][oB] = *(const bf16x8*)(gBh);
        *(bf16x8*)&sBlo[0][oB] = *(const bf16x8*)(gBl);
    }
    __syncthreads();

    for (int it = 0; it < NITP; ++it) {
        const int cur = it & 1;
        const bool more = (it + 1) < NITP;

        // issue next-tile loads first (consumed after the compute phase)
        float4 na;
        bf16x8 nbh, nbl;
        if (more) {
            const int k0 = (it + 1) * 32;
            if (doA) na = *(const float4*)(gA + k0);
            nbh = *(const bf16x8*)(gBh + k0);
            nbl = *(const bf16x8*)(gBl + k0);
        }

        // ---- compute on current buffer: 4 ds_read_b128, 4 MFMAs
        bf16x8 ahi = *(const bf16x8*)&sAhi[cur][aoff];
        bf16x8 alo = *(const bf16x8*)&sAlo[cur][aoff];
        bf16x8 bhi = *(const bf16x8*)&sBhi[cur][boff];
        bf16x8 blo = *(const bf16x8*)&sBlo[cur][boff];
        // 4-term exact split, same accumulation order as the passing kernel
        acc = mfma16(ahi, bhi, acc);
        acc = mfma16(ahi, blo, acc);
        acc = mfma16(alo, bhi, acc);
        acc = mfma16(alo, blo, acc);

        if (more) {
            const int nb = cur ^ 1;
            if (doA) {
                bf16x4 h, l;
                cvt_split(na, h, l);
                *(bf16x4*)&sAhi[nb][oA] = h;
                *(bf16x4*)&sAlo[nb][oA] = l;
            }
            *(bf16x8*)&sBhi[nb][oB] = nbh;
            *(bf16x8*)&sBlo[nb][oB] = nbl;
        }
        __syncthreads();
    }

    // ---- scatter logits: C/D layout col=lane&15 (expert), row=fq*4+reg (token)
    #pragma unroll
    for (int r = 0; r < 4; ++r) {
        const int tokl = fq * 4 + r;          // 0..15
        const int expl = wv * 16 + fm;        // 0..63
        sLog[tokl * SL + expl] = acc[r];
    }
    __syncthreads();

    // ---- softmax/top-2: 16 lanes per token, 4 experts per lane
    const int g = tid >> 4;       // token 0..15
    const int l = tid & 15;
    float* Lrow = &sLog[g * SL + l * 4];
    float lv[4];
    float m = -3.0e38f;
    #pragma unroll
    for (int c = 0; c < 4; ++c) { lv[c] = Lrow[c]; m = fmaxf(m, lv[c]); }
    m = fmaxf(m, __shfl_xor(m, 1, 64));
    m = fmaxf(m, __shfl_xor(m, 2, 64));
    m = fmaxf(m, __shfl_xor(m, 4, 64));
    m = fmaxf(m, __shfl_xor(m, 8, 64));

    float v1 = -3.0e38f, v2 = -3.0e38f; int i1 = 0, i2 = 0;
    float ssum = 0.0f;
    #pragma unroll
    for (int c = 0; c < 4; ++c) {
        const float val = lv[c]; const int idx = l * 4 + c;
        const float ev = __expf(val - m);
        Lrow[c] = ev;               // overwrite logits with exp(l - m)
        ssum += ev;
        if (val > v1) { v2 = v1; i2 = i1; v1 = val; i1 = idx; }
        else if (val > v2) { v2 = val; i2 = idx; }
    }
    ssum += __shfl_xor(ssum, 1, 64);
    ssum += __shfl_xor(ssum, 2, 64);
    ssum += __shfl_xor(ssum, 4, 64);
    ssum += __shfl_xor(ssum, 8, 64);

    #pragma unroll
    for (int s = 1; s <= 8; s <<= 1) {
        const float ov1 = __shfl_xor(v1, s, 64);
        const int   oi1 = __shfl_xor(i1, s, 64);
        const float ov2 = __shfl_xor(v2, s, 64);
        const int   oi2 = __shfl_xor(i2, s, 64);
        float n1, n2; int ni1, ni2;
        const bool ofirst = (ov1 > v1) || (ov1 == v1 && oi1 < i1);
        if (ofirst) {
            n1 = ov1; ni1 = oi1;
            const bool osec = (ov2 > v1) || (ov2 == v1 && oi2 < i1);
            n2 = osec ? ov2 : v1; ni2 = osec ? oi2 : i1;
        } else {
            n1 = v1; ni1 = i1;
            const bool asec = (v2 > ov1) || (v2 == ov1 && i2 < oi1);
            n2 = asec ? v2 : ov1; ni2 = asec ? i2 : oi1;
        }
        v1 = n1; i1 = ni1; v2 = n2; i2 = ni2;
    }

    if (l == 0) {
        const float e1 = __expf(v1 - m), e2 = __expf(v2 - m);
        const float winv = 1.0f / (e1 + e2);
        const int token = t0 + g;
        out[2 * token]     = e1 * winv;
        out[2 * token + 1] = e2 * winv;
        out[2 * NTOK + 2 * token]     = (float)i1;   // indices as f32 (concat promotion)
        out[2 * NTOK + 2 * token + 1] = (float)i2;
        const float lse = m + __logf(ssum);
        atomicAdd(&sZ, lse * lse);
        atomicAdd(&sCnt[i1], 1.0f);
        atomicAdd(&sCnt[i2], 1.0f);
        sInv[g] = 1.0f / ssum;
    }
    __syncthreads();

    // ---- block-local P sums over 16 tokens, then global atomics
    {
        const int e = tid & 63;
        const int q = tid >> 6;     // 0..3
        float part = 0.0f;
        #pragma unroll
        for (int t = 0; t < 4; ++t) {
            const int tok = q * 4 + t;
            part += sLog[tok * SL + e] * sInv[tok];
        }
        sPp[q * 64 + e] = part;
    }
    __syncthreads();
    if (tid < 64) {
        const float ps = sPp[tid] + sPp[64 + tid] + sPp[128 + tid] + sPp[192 + tid];
        atomicAdd(&ws[tid], ps);             // sum of probs per expert
        atomicAdd(&ws[64 + tid], sCnt[tid]); // top-2 counts per expert
    }
    if (tid == 0) atomicAdd(&ws[128], sZ);
}

// Fallback (ws too small for B copies): round-0 verified kernel.
__global__ __launch_bounds__(256) void router_fb_kernel(
    const float* __restrict__ hs,
    const float* __restrict__ Wg,
    float* __restrict__ out,
    float* __restrict__ ws)
{
    __shared__ __bf16 sAhi[2][TFB * SAB];
    __shared__ __bf16 sAlo[2][TFB * SAB];
    __shared__ __bf16 sBhi[2][NE * SAB];
    __shared__ __bf16 sBlo[2][NE * SAB];
    __shared__ float  sLog[TFB * SL];
    __shared__ float  sInv[TFB];
    __shared__ float  sPp[4 * 64];
    __shared__ float  sCnt[64];
    __shared__ float  sZ;

    const int tid = threadIdx.x;
    const int t0  = blockIdx.x * TFB;

    if (tid < 64) sCnt[tid] = 0.0f;
    if (tid == 0) sZ = 0.0f;

    const int r1 = tid >> 3;
    const int c4 = (tid & 7) * 4;
    const float* gA = hs + (size_t)(t0 + r1) * HD + c4;
    const float* gB = Wg + (size_t)r1 * HD + c4;
    const int oA  = r1 * SAB + c4;
    const int oB1 = r1 * SAB + c4;
    const int oB2 = (r1 + 32) * SAB + c4;

    const int lane = tid & 63;
    const int wv   = tid >> 6;
    const int wr   = (wv >> 1) * 16;
    const int wc   = (wv & 1) * 32;
    const int fm   = lane & 15;
    const int fq   = lane >> 4;
    const int fk   = fq * 8;

    f32x4 acc[2];
    acc[0] = (f32x4){0.f, 0.f, 0.f, 0.f};
    acc[1] = (f32x4){0.f, 0.f, 0.f, 0.f};

    {
        float4 a0 = *(const float4*)(gA);
        float4 b0 = *(const float4*)(gB);
        float4 b1 = *(const float4*)(gB + 32 * HD);
        bf16x4 h, l;
        cvt_split(a0, h, l); *(bf16x4*)&sAhi[0][oA]  = h; *(bf16x4*)&sAlo[0][oA]  = l;
        cvt_split(b0, h, l); *(bf16x4*)&sBhi[0][oB1] = h; *(bf16x4*)&sBlo[0][oB1] = l;
        cvt_split(b1, h, l); *(bf16x4*)&sBhi[0][oB2] = h; *(bf16x4*)&sBlo[0][oB2] = l;
    }
    __syncthreads();

    for (int it = 0; it < NIT; ++it) {
        const int cur = it & 1;
        const bool more = (it + 1) < NIT;
        float4 na0, nb0, nb1;
        if (more) {
            const int k0 = (it + 1) * 32;
            na0 = *(const float4*)(gA + k0);
            nb0 = *(const float4*)(gB + k0);
            nb1 = *(const float4*)(gB + 32 * HD + k0);
        }

        bf16x8 ahi, alo, bhi[2], blo[2];
        {
            const int aoff = (wr + fm) * SAB + fk;
            ahi = *(const bf16x8*)&sAhi[cur][aoff];
            alo = *(const bf16x8*)&sAlo[cur][aoff];
        }
        #pragma unroll
        for (int j = 0; j < 2; ++j) {
            const int boff = (wc + j * 16 + fm) * SAB + fk;
            bhi[j] = *(const bf16x8*)&sBhi[cur][boff];
            blo[j] = *(const bf16x8*)&sBlo[cur][boff];
        }
        #pragma unroll
        for (int j = 0; j < 2; ++j) {
            acc[j] = mfma16(ahi, bhi[j], acc[j]);
            acc[j] = mfma16(ahi, blo[j], acc[j]);
            acc[j] = mfma16(alo, bhi[j], acc[j]);
            acc[j] = mfma16(alo, blo[j], acc[j]);
        }

        if (more) {
            const int nb = cur ^ 1;
            bf16x4 h, l;
            cvt_split(na0, h, l); *(bf16x4*)&sAhi[nb][oA]  = h; *(bf16x4*)&sAlo[nb][oA]  = l;
            cvt_split(nb0, h, l); *(bf16x4*)&sBhi[nb][oB1] = h; *(bf16x4*)&sBlo[nb][oB1] = l;
            cvt_split(nb1, h, l); *(bf16x4*)&sBhi[nb][oB2] = h; *(bf16x4*)&sBlo[nb][oB2] = l;
        }
        __syncthreads();
    }

    #pragma unroll
    for (int j = 0; j < 2; ++j)
        #pragma unroll
        for (int r = 0; r < 4; ++r) {
            const int tokl = wr + fq * 4 + r;
            const int expl = wc + j * 16 + fm;
            sLog[tokl * SL + expl] = acc[j][r];
        }
    __syncthreads();

    const int g = tid >> 3;
    const int l = tid & 7;
    float* Lrow = &sLog[g * SL + l * 8];
    float lv[8];
    float m = -3.0e38f;
    #pragma unroll
    for (int c = 0; c < 8; ++c) { lv[c] = Lrow[c]; m = fmaxf(m, lv[c]); }
    m = fmaxf(m, __shfl_xor(m, 1, 64));
    m = fmaxf(m, __shfl_xor(m, 2, 64));
    m = fmaxf(m, __shfl_xor(m, 4, 64));

    float v1 = -3.0e38f, v2 = -3.0e38f; int i1 = 0, i2 = 0;
    float ssum = 0.0f;
    #pragma unroll
    for (int c = 0; c < 8; ++c) {
        const float val = lv[c]; const int idx = l * 8 + c;
        const float ev = __expf(val - m);
        Lrow[c] = ev;
        ssum += ev;
        if (val > v1) { v2 = v1; i2 = i1; v1 = val; i1 = idx; }
        else if (val > v2) { v2 = val; i2 = idx; }
    }
    ssum += __shfl_xor(ssum, 1, 64);
    ssum += __shfl_xor(ssum, 2, 64);
    ssum += __shfl_xor(ssum, 4, 64);

    #pragma unroll
    for (int s = 1; s <= 4; s <<= 1) {
        const float ov1 = __shfl_xor(v1, s, 64);
        const int   oi1 = __shfl_xor(i1, s, 64);
        const float ov2 = __shfl_xor(v2, s, 64);
        const int   oi2 = __shfl_xor(i2, s, 64);
        float n1, n2; int ni1, ni2;
        const bool ofirst = (ov1 > v1) || (ov1 == v1 && oi1 < i1);
        if (ofirst) {
            n1 = ov1; ni1 = oi1;
            const bool osec = (ov2 > v1) || (ov2 == v1 && oi2 < i1);
            n2 = osec ? ov2 : v1; ni2 = osec ? oi2 : i1;
        } else {
            n1 = v1; ni1 = i1;
            const bool asec = (v2 > ov1) || (v2 == ov1 && i2 < oi1);
            n2 = asec ? v2 : ov1; ni2 = asec ? i2 : oi1;
        }
        v1 = n1; i1 = ni1; v2 = n2; i2 = ni2;
    }

    if (l == 0) {
        const float e1 = __expf(v1 - m), e2 = __expf(v2 - m);
        const float winv = 1.0f / (e1 + e2);
        const int token = t0 + g;
        out[2 * token]     = e1 * winv;
        out[2 * token + 1] = e2 * winv;
        out[2 * NTOK + 2 * token]     = (float)i1;
        out[2 * NTOK + 2 * token + 1] = (float)i2;
        const float lse = m + __logf(ssum);
        atomicAdd(&sZ, lse * lse);
        atomicAdd(&sCnt[i1], 1.0f);
        atomicAdd(&sCnt[i2], 1.0f);
        sInv[g] = 1.0f / ssum;
    }
    __syncthreads();

    {
        const int e = tid & 63;
        const int q = tid >> 6;
        float part = 0.0f;
        #pragma unroll
        for (int t = 0; t < 8; ++t) {
            const int tok = q * 8 + t;
            part += sLog[tok * SL + e] * sInv[tok];
        }
        sPp[q * 64 + e] = part;
    }
    __syncthreads();
    if (tid < 64) {
        const float ps = sPp[tid] + sPp[64 + tid] + sPp[128 + tid] + sPp[192 + tid];
        atomicAdd(&ws[tid], ps);
        atomicAdd(&ws[64 + tid], sCnt[tid]);
    }
    if (tid == 0) atomicAdd(&ws[128], sZ);
}

__global__ void finalize_kernel(const float* __restrict__ ws, float* __restrict__ out) {
    const int e = threadIdx.x;   // 64 threads, one wave
    const float P = ws[e] * (1.0f / NTOK);
    const float f = ws[64 + e] * (1.0f / (NTOK * 2));
    float term = f * P;
    #pragma unroll
    for (int s = 32; s >= 1; s >>= 1) term += __shfl_xor(term, s, 64);
    if (e == 0) {
        const float lb = 64.0f * term;
        const float z  = ws[128] * (1.0f / NTOK);
        out[4 * NTOK] = 0.001f * lb + 0.001f * z;
    }
}

extern "C" void kernel_launch(void* const* d_in, const int* in_sizes, int n_in,
                              void* d_out, int out_size, void* d_ws, size_t ws_size,
                              hipStream_t stream) {
    const float* hs = (const float*)d_in[0];
    const float* Wg = (const float*)d_in[1];
    float* out = (float*)d_out;
    float* ws  = (float*)d_ws;

    const size_t need = (size_t)WS_ACC_FLOATS * sizeof(float)
                      + (size_t)B_ELEMS * 2 * sizeof(__bf16);
    if (ws_size >= need) {
        const __bf16* Bhi = (const __bf16*)(ws + WS_ACC_FLOATS);
        const __bf16* Blo = Bhi + B_ELEMS;
        hipLaunchKernelGGL(prep_kernel, dim3(128), dim3(256), 0, stream, Wg, ws);
        hipLaunchKernelGGL(router_pre_kernel, dim3(NBLK_PRE), dim3(256), 0, stream,
                           hs, Bhi, Blo, out, ws);
    } else {
        hipLaunchKernelGGL(zero_ws_kernel, dim3(1), dim3(256), 0, stream, ws);
        hipLaunchKernelGGL(router_fb_kernel, dim3(NBLK_FB), dim3(256), 0, stream,
                           hs, Wg, out, ws);
    }
    hipLaunchKernelGGL(finalize_kernel, dim3(1), dim3(64), 0, stream, ws, out);
}

// Round 5
// 394.137 us; speedup vs baseline: 1.2927x; 1.1623x over previous
//
#include <hip/hip_runtime.h>
#include <hip/hip_bf16.h>

#define NTOK 16384
#define HD   4096
#define NE   64

// PRE path: 32 tokens/block, BK=64 -> 64 barriered iterations (half of round-0)
#define TTILE 32
#define NBLK (NTOK / TTILE)   // 512 blocks -> 2 blocks/CU
#define BK    64
#define NITP  (HD / BK)       // 64 k-tiles

// FB path (round-0 verified): BK=32
#define NIT  (HD / 32)

// LDS row strides (elements)
#define SAB 40   // FB: 32 K + 8 pad
#define SA2 72   // PRE: 64 K + 8 pad -> 144 B rows (16B-aligned; reads 2-way free)
#define SL  68   // float stride for logits tiles

// ws layout (floats): [0,64)=P_sum, [64,128)=counts, [128]=z_sum, pad to 192,
// then Bhi (bf16, NE*HD), then Blo (bf16, NE*HD). ~1.05 MB total.
#define WS_ACC_FLOATS 192
#define B_ELEMS (NE * HD)

typedef __bf16 bf16x8 __attribute__((ext_vector_type(8)));
typedef __bf16 bf16x4 __attribute__((ext_vector_type(4)));
typedef float  f32x4  __attribute__((ext_vector_type(4)));

__device__ __forceinline__ f32x4 mfma16(bf16x8 a, bf16x8 b, f32x4 c) {
    return __builtin_amdgcn_mfma_f32_16x16x32_bf16(a, b, c, 0, 0, 0);
}

__device__ __forceinline__ void cvt_split(float4 v, bf16x4& hi, bf16x4& lo) {
    float x[4] = {v.x, v.y, v.z, v.w};
    #pragma unroll
    for (int e = 0; e < 4; ++e) {
        __bf16 h = (__bf16)x[e];        // RNE
        hi[e] = h;
        lo[e] = (__bf16)(x[e] - (float)h);
    }
}

__device__ __forceinline__ void cvt8(float4 x0, float4 x1, bf16x8& hi, bf16x8& lo) {
    bf16x4 h, l;
    cvt_split(x0, h, l);
    #pragma unroll
    for (int e = 0; e < 4; ++e) { hi[e] = h[e]; lo[e] = l[e]; }
    cvt_split(x1, h, l);
    #pragma unroll
    for (int e = 0; e < 4; ++e) { hi[4 + e] = h[e]; lo[4 + e] = l[e]; }
}

__global__ void zero_ws_kernel(float* ws) {
    int i = threadIdx.x;
    if (i < 129) ws[i] = 0.0f;
}

// One-shot: zero accumulators + convert W_gate fp32 -> bf16 hi/lo in ws.
__global__ __launch_bounds__(256) void prep_kernel(
    const float* __restrict__ Wg, float* __restrict__ ws)
{
    const int tid = threadIdx.x;
    if (blockIdx.x == 0 && tid < 129) ws[tid] = 0.0f;
    __bf16* Bhi = (__bf16*)(ws + WS_ACC_FLOATS);
    __bf16* Blo = Bhi + B_ELEMS;
    const int i = (blockIdx.x * 256 + tid) * 8;
    float4 v0 = *(const float4*)(Wg + i);
    float4 v1 = *(const float4*)(Wg + i + 4);
    bf16x4 h0, l0, h1, l1;
    cvt_split(v0, h0, l0);
    cvt_split(v1, h1, l1);
    *(bf16x4*)(Bhi + i)     = h0;
    *(bf16x4*)(Bhi + i + 4) = h1;
    *(bf16x4*)(Blo + i)     = l0;
    *(bf16x4*)(Blo + i + 4) = l1;
}

// PRE router: round-0 champion structure (barriered LDS double-buffer,
// 2 blocks/CU) with BK=64 -> half the barrier/vmcnt(0) drains, 16 MFMA/wave
// per barrier, and B staged as a pure bf16 copy from the pre-split arrays.
__global__ __launch_bounds__(256) void router_pre_kernel(
    const float* __restrict__ hs,
    const __bf16* __restrict__ Bhi,
    const __bf16* __restrict__ Blo,
    float* __restrict__ out,
    float* __restrict__ ws)
{
    __shared__ __bf16 sAhi[2][TTILE * SA2];  //  9,216 B
    __shared__ __bf16 sAlo[2][TTILE * SA2];  //  9,216 B
    __shared__ __bf16 sBhi[2][NE * SA2];     // 18,432 B
    __shared__ __bf16 sBlo[2][NE * SA2];     // 18,432 B
    __shared__ float  sLog[TTILE * SL];      //  8,704 B
    __shared__ float  sInv[TTILE];
    __shared__ float  sPp[4 * 64];
    __shared__ float  sCnt[64];
    __shared__ float  sZ;
    // total ~65.4 KB -> 2 blocks/CU

    const int tid = threadIdx.x;
    const int t0  = blockIdx.x * TTILE;

    if (tid < 64) sCnt[tid] = 0.0f;
    if (tid == 0) sZ = 0.0f;

    // ---- A staging: 256 threads, each loads 8 floats (2 float4) per iter
    const int rowA = tid >> 3;           // token row 0..31
    const int colA = (tid & 7) * 8;      // k offset (floats) within 64
    const float* gA = hs + (size_t)(t0 + rowA) * HD + colA;
    const int oAw = rowA * SA2 + colA;   // LDS elem offset (byte 16-aligned)

    // ---- B staging: 256 threads, each copies 2x16B of Bhi + 2x16B of Blo
    const int eb = tid >> 2;             // expert 0..63
    const int cB = (tid & 3) * 8;        // k offset (elems) within 64: c and c+32
    const __bf16* gBh = Bhi + (size_t)eb * HD + cB;
    const __bf16* gBl = Blo + (size_t)eb * HD + cB;
    const int oBw = eb * SA2 + cB;

    // ---- wave tile: 16 tok x 32 exp (1x2 MFMA tiles), 4 waves cover 32x64
    const int lane = tid & 63;
    const int wv   = tid >> 6;
    const int wr   = (wv >> 1) * 16;     // token offset: 0 or 16
    const int wc   = (wv & 1) * 32;      // expert offset: 0 or 32
    const int fm   = lane & 15;
    const int fq   = lane >> 4;          // 0..3
    const int fk   = fq * 8;             // k offset within 32-subtile

    f32x4 acc[2];
    acc[0] = (f32x4){0.f, 0.f, 0.f, 0.f};
    acc[1] = (f32x4){0.f, 0.f, 0.f, 0.f};

    // ---- prologue: stage k-tile 0 into buffer 0
    {
        float4 a0 = *(const float4*)(gA);
        float4 a1 = *(const float4*)(gA + 4);
        bf16x8 h, l;
        cvt8(a0, a1, h, l);
        *(bf16x8*)&sAhi[0][oAw] = h;
        *(bf16x8*)&sAlo[0][oAw] = l;
        *(bf16x8*)&sBhi[0][oBw]      = *(const bf16x8*)(gBh);
        *(bf16x8*)&sBhi[0][oBw + 32] = *(const bf16x8*)(gBh + 32);
        *(bf16x8*)&sBlo[0][oBw]      = *(const bf16x8*)(gBl);
        *(bf16x8*)&sBlo[0][oBw + 32] = *(const bf16x8*)(gBl + 32);
    }
    __syncthreads();

    #pragma unroll 2
    for (int it = 0; it < NITP; ++it) {
        const int cur = it & 1;
        const bool more = (it + 1) < NITP;

        // issue next-tile loads first (A: 2 float4; B: 4 bf16x8)
        float4 na0, na1;
        bf16x8 nb0, nb1, nb2, nb3;
        if (more) {
            const int k0 = (it + 1) * BK;
            na0 = *(const float4*)(gA + k0);
            na1 = *(const float4*)(gA + k0 + 4);
            nb0 = *(const bf16x8*)(gBh + k0);
            nb1 = *(const bf16x8*)(gBh + k0 + 32);
            nb2 = *(const bf16x8*)(gBl + k0);
            nb3 = *(const bf16x8*)(gBl + k0 + 32);
        }

        // ---- compute on current buffer: 12 ds_read_b128, 16 MFMAs
        #pragma unroll
        for (int kk = 0; kk < 2; ++kk) {
            const int ao = (wr + fm) * SA2 + kk * 32 + fk;
            bf16x8 ahi = *(const bf16x8*)&sAhi[cur][ao];
            bf16x8 alo = *(const bf16x8*)&sAlo[cur][ao];
            const int bo0 = (wc + fm) * SA2 + kk * 32 + fk;
            const int bo1 = (wc + 16 + fm) * SA2 + kk * 32 + fk;
            bf16x8 bh0 = *(const bf16x8*)&sBhi[cur][bo0];
            bf16x8 bh1 = *(const bf16x8*)&sBhi[cur][bo1];
            bf16x8 bl0 = *(const bf16x8*)&sBlo[cur][bo0];
            bf16x8 bl1 = *(const bf16x8*)&sBlo[cur][bo1];
            // 4-term exact split; per-acc term order (hh,hl,lh,ll) and k-order
            // identical to round-0 -> bit-identical accumulation
            acc[0] = mfma16(ahi, bh0, acc[0]);
            acc[1] = mfma16(ahi, bh1, acc[1]);
            acc[0] = mfma16(ahi, bl0, acc[0]);
            acc[1] = mfma16(ahi, bl1, acc[1]);
            acc[0] = mfma16(alo, bh0, acc[0]);
            acc[1] = mfma16(alo, bh1, acc[1]);
            acc[0] = mfma16(alo, bl0, acc[0]);
            acc[1] = mfma16(alo, bl1, acc[1]);
        }

        if (more) {
            const int nb = cur ^ 1;
            bf16x8 h, l;
            cvt8(na0, na1, h, l);
            *(bf16x8*)&sAhi[nb][oAw] = h;
            *(bf16x8*)&sAlo[nb][oAw] = l;
            *(bf16x8*)&sBhi[nb][oBw]      = nb0;
            *(bf16x8*)&sBhi[nb][oBw + 32] = nb1;
            *(bf16x8*)&sBlo[nb][oBw]      = nb2;
            *(bf16x8*)&sBlo[nb][oBw + 32] = nb3;
        }
        __syncthreads();
    }

    // ---- scatter logits to LDS: C/D layout col=lane&15 (expert), row=fq*4+reg
    #pragma unroll
    for (int j = 0; j < 2; ++j)
        #pragma unroll
        for (int r = 0; r < 4; ++r) {
            const int tokl = wr + fq * 4 + r;
            const int expl = wc + j * 16 + fm;
            sLog[tokl * SL + expl] = acc[j][r];
        }
    __syncthreads();

    // ---- phase 2a: softmax/top-2; 8 lanes per token, 8 experts per lane
    const int g = tid >> 3;       // token 0..31
    const int l = tid & 7;
    float* Lrow = &sLog[g * SL + l * 8];
    float lv[8];
    float m = -3.0e38f;
    #pragma unroll
    for (int c = 0; c < 8; ++c) { lv[c] = Lrow[c]; m = fmaxf(m, lv[c]); }
    m = fmaxf(m, __shfl_xor(m, 1, 64));
    m = fmaxf(m, __shfl_xor(m, 2, 64));
    m = fmaxf(m, __shfl_xor(m, 4, 64));

    float v1 = -3.0e38f, v2 = -3.0e38f; int i1 = 0, i2 = 0;
    float ssum = 0.0f;
    #pragma unroll
    for (int c = 0; c < 8; ++c) {
        const float val = lv[c]; const int idx = l * 8 + c;
        const float ev = __expf(val - m);
        Lrow[c] = ev;               // overwrite logits with exp(l - m)
        ssum += ev;
        if (val > v1) { v2 = v1; i2 = i1; v1 = val; i1 = idx; }
        else if (val > v2) { v2 = val; i2 = idx; }
    }
    ssum += __shfl_xor(ssum, 1, 64);
    ssum += __shfl_xor(ssum, 2, 64);
    ssum += __shfl_xor(ssum, 4, 64);

    #pragma unroll
    for (int s = 1; s <= 4; s <<= 1) {
        const float ov1 = __shfl_xor(v1, s, 64);
        const int   oi1 = __shfl_xor(i1, s, 64);
        const float ov2 = __shfl_xor(v2, s, 64);
        const int   oi2 = __shfl_xor(i2, s, 64);
        float n1, n2; int ni1, ni2;
        const bool ofirst = (ov1 > v1) || (ov1 == v1 && oi1 < i1);
        if (ofirst) {
            n1 = ov1; ni1 = oi1;
            const bool osec = (ov2 > v1) || (ov2 == v1 && oi2 < i1);
            n2 = osec ? ov2 : v1; ni2 = osec ? oi2 : i1;
        } else {
            n1 = v1; ni1 = i1;
            const bool asec = (v2 > ov1) || (v2 == ov1 && i2 < oi1);
            n2 = asec ? v2 : ov1; ni2 = asec ? i2 : oi1;
        }
        v1 = n1; i1 = ni1; v2 = n2; i2 = ni2;
    }

    if (l == 0) {
        const float e1 = __expf(v1 - m), e2 = __expf(v2 - m);
        const float winv = 1.0f / (e1 + e2);
        const int token = t0 + g;
        out[2 * token]     = e1 * winv;
        out[2 * token + 1] = e2 * winv;
        out[2 * NTOK + 2 * token]     = (float)i1;   // indices as f32 (concat promotion)
        out[2 * NTOK + 2 * token + 1] = (float)i2;
        const float lse = m + __logf(ssum);
        atomicAdd(&sZ, lse * lse);
        atomicAdd(&sCnt[i1], 1.0f);
        atomicAdd(&sCnt[i2], 1.0f);
        sInv[g] = 1.0f / ssum;
    }
    __syncthreads();

    // ---- phase 2b: block-local P sums over 32 tokens, then global atomics
    {
        const int e = tid & 63;
        const int q = tid >> 6;
        float part = 0.0f;
        #pragma unroll
        for (int t = 0; t < 8; ++t) {
            const int tok = q * 8 + t;
            part += sLog[tok * SL + e] * sInv[tok];
        }
        sPp[q * 64 + e] = part;
    }
    __syncthreads();
    if (tid < 64) {
        const float ps = sPp[tid] + sPp[64 + tid] + sPp[128 + tid] + sPp[192 + tid];
        atomicAdd(&ws[tid], ps);             // sum of probs per expert
        atomicAdd(&ws[64 + tid], sCnt[tid]); // top-2 counts per expert
    }
    if (tid == 0) atomicAdd(&ws[128], sZ);
}

// Fallback (ws too small for B copies): round-0 verified kernel.
__global__ __launch_bounds__(256) void router_fb_kernel(
    const float* __restrict__ hs,
    const float* __restrict__ Wg,
    float* __restrict__ out,
    float* __restrict__ ws)
{
    __shared__ __bf16 sAhi[2][TTILE * SAB];
    __shared__ __bf16 sAlo[2][TTILE * SAB];
    __shared__ __bf16 sBhi[2][NE * SAB];
    __shared__ __bf16 sBlo[2][NE * SAB];
    __shared__ float  sLog[TTILE * SL];
    __shared__ float  sInv[TTILE];
    __shared__ float  sPp[4 * 64];
    __shared__ float  sCnt[64];
    __shared__ float  sZ;

    const int tid = threadIdx.x;
    const int t0  = blockIdx.x * TTILE;

    if (tid < 64) sCnt[tid] = 0.0f;
    if (tid == 0) sZ = 0.0f;

    const int r1 = tid >> 3;
    const int c4 = (tid & 7) * 4;
    const float* gA = hs + (size_t)(t0 + r1) * HD + c4;
    const float* gB = Wg + (size_t)r1 * HD + c4;
    const int oA  = r1 * SAB + c4;
    const int oB1 = r1 * SAB + c4;
    const int oB2 = (r1 + 32) * SAB + c4;

    const int lane = tid & 63;
    const int wv   = tid >> 6;
    const int wr   = (wv >> 1) * 16;
    const int wc   = (wv & 1) * 32;
    const int fm   = lane & 15;
    const int fq   = lane >> 4;
    const int fk   = fq * 8;

    f32x4 acc[2];
    acc[0] = (f32x4){0.f, 0.f, 0.f, 0.f};
    acc[1] = (f32x4){0.f, 0.f, 0.f, 0.f};

    {
        float4 a0 = *(const float4*)(gA);
        float4 b0 = *(const float4*)(gB);
        float4 b1 = *(const float4*)(gB + 32 * HD);
        bf16x4 h, l;
        cvt_split(a0, h, l); *(bf16x4*)&sAhi[0][oA]  = h; *(bf16x4*)&sAlo[0][oA]  = l;
        cvt_split(b0, h, l); *(bf16x4*)&sBhi[0][oB1] = h; *(bf16x4*)&sBlo[0][oB1] = l;
        cvt_split(b1, h, l); *(bf16x4*)&sBhi[0][oB2] = h; *(bf16x4*)&sBlo[0][oB2] = l;
    }
    __syncthreads();

    for (int it = 0; it < NIT; ++it) {
        const int cur = it & 1;
        const bool more = (it + 1) < NIT;
        float4 na0, nb0, nb1;
        if (more) {
            const int k0 = (it + 1) * 32;
            na0 = *(const float4*)(gA + k0);
            nb0 = *(const float4*)(gB + k0);
            nb1 = *(const float4*)(gB + 32 * HD + k0);
        }

        bf16x8 ahi, alo, bhi[2], blo[2];
        {
            const int aoff = (wr + fm) * SAB + fk;
            ahi = *(const bf16x8*)&sAhi[cur][aoff];
            alo = *(const bf16x8*)&sAlo[cur][aoff];
        }
        #pragma unroll
        for (int j = 0; j < 2; ++j) {
            const int boff = (wc + j * 16 + fm) * SAB + fk;
            bhi[j] = *(const bf16x8*)&sBhi[cur][boff];
            blo[j] = *(const bf16x8*)&sBlo[cur][boff];
        }
        #pragma unroll
        for (int j = 0; j < 2; ++j) {
            acc[j] = mfma16(ahi, bhi[j], acc[j]);
            acc[j] = mfma16(ahi, blo[j], acc[j]);
            acc[j] = mfma16(alo, bhi[j], acc[j]);
            acc[j] = mfma16(alo, blo[j], acc[j]);
        }

        if (more) {
            const int nb = cur ^ 1;
            bf16x4 h, l;
            cvt_split(na0, h, l); *(bf16x4*)&sAhi[nb][oA]  = h; *(bf16x4*)&sAlo[nb][oA]  = l;
            cvt_split(nb0, h, l); *(bf16x4*)&sBhi[nb][oB1] = h; *(bf16x4*)&sBlo[nb][oB1] = l;
            cvt_split(nb1, h, l); *(bf16x4*)&sBhi[nb][oB2] = h; *(bf16x4*)&sBlo[nb][oB2] = l;
        }
        __syncthreads();
    }

    #pragma unroll
    for (int j = 0; j < 2; ++j)
        #pragma unroll
        for (int r = 0; r < 4; ++r) {
            const int tokl = wr + fq * 4 + r;
            const int expl = wc + j * 16 + fm;
            sLog[tokl * SL + expl] = acc[j][r];
        }
    __syncthreads();

    const int g = tid >> 3;
    const int l = tid & 7;
    float* Lrow = &sLog[g * SL + l * 8];
    float lv[8];
    float m = -3.0e38f;
    #pragma unroll
    for (int c = 0; c < 8; ++c) { lv[c] = Lrow[c]; m = fmaxf(m, lv[c]); }
    m = fmaxf(m, __shfl_xor(m, 1, 64));
    m = fmaxf(m, __shfl_xor(m, 2, 64));
    m = fmaxf(m, __shfl_xor(m, 4, 64));

    float v1 = -3.0e38f, v2 = -3.0e38f; int i1 = 0, i2 = 0;
    float ssum = 0.0f;
    #pragma unroll
    for (int c = 0; c < 8; ++c) {
        const float val = lv[c]; const int idx = l * 8 + c;
        const float ev = __expf(val - m);
        Lrow[c] = ev;
        ssum += ev;
        if (val > v1) { v2 = v1; i2 = i1; v1 = val; i1 = idx; }
        else if (val > v2) { v2 = val; i2 = idx; }
    }
    ssum += __shfl_xor(ssum, 1, 64);
    ssum += __shfl_xor(ssum, 2, 64);
    ssum += __shfl_xor(ssum, 4, 64);

    #pragma unroll
    for (int s = 1; s <= 4; s <<= 1) {
        const float ov1 = __shfl_xor(v1, s, 64);
        const int   oi1 = __shfl_xor(i1, s, 64);
        const float ov2 = __shfl_xor(v2, s, 64);
        const int   oi2 = __shfl_xor(i2, s, 64);
        float n1, n2; int ni1, ni2;
        const bool ofirst = (ov1 > v1) || (ov1 == v1 && oi1 < i1);
        if (ofirst) {
            n1 = ov1; ni1 = oi1;
            const bool osec = (ov2 > v1) || (ov2 == v1 && oi2 < i1);
            n2 = osec ? ov2 : v1; ni2 = osec ? oi2 : i1;
        } else {
            n1 = v1; ni1 = i1;
            const bool asec = (v2 > ov1) || (v2 == ov1 && i2 < oi1);
            n2 = asec ? v2 : ov1; ni2 = asec ? i2 : oi1;
        }
        v1 = n1; i1 = ni1; v2 = n2; i2 = ni2;
    }

    if (l == 0) {
        const float e1 = __expf(v1 - m), e2 = __expf(v2 - m);
        const float winv = 1.0f / (e1 + e2);
        const int token = t0 + g;
        out[2 * token]     = e1 * winv;
        out[2 * token + 1] = e2 * winv;
        out[2 * NTOK + 2 * token]     = (float)i1;
        out[2 * NTOK + 2 * token + 1] = (float)i2;
        const float lse = m + __logf(ssum);
        atomicAdd(&sZ, lse * lse);
        atomicAdd(&sCnt[i1], 1.0f);
        atomicAdd(&sCnt[i2], 1.0f);
        sInv[g] = 1.0f / ssum;
    }
    __syncthreads();

    {
        const int e = tid & 63;
        const int q = tid >> 6;
        float part = 0.0f;
        #pragma unroll
        for (int t = 0; t < 8; ++t) {
            const int tok = q * 8 + t;
            part += sLog[tok * SL + e] * sInv[tok];
        }
        sPp[q * 64 + e] = part;
    }
    __syncthreads();
    if (tid < 64) {
        const float ps = sPp[tid] + sPp[64 + tid] + sPp[128 + tid] + sPp[192 + tid];
        atomicAdd(&ws[tid], ps);
        atomicAdd(&ws[64 + tid], sCnt[tid]);
    }
    if (tid == 0) atomicAdd(&ws[128], sZ);
}

__global__ void finalize_kernel(const float* __restrict__ ws, float* __restrict__ out) {
    const int e = threadIdx.x;   // 64 threads, one wave
    const float P = ws[e] * (1.0f / NTOK);
    const float f = ws[64 + e] * (1.0f / (NTOK * 2));
    float term = f * P;
    #pragma unroll
    for (int s = 32; s >= 1; s >>= 1) term += __shfl_xor(term, s, 64);
    if (e == 0) {
        const float lb = 64.0f * term;
        const float z  = ws[128] * (1.0f / NTOK);
        out[4 * NTOK] = 0.001f * lb + 0.001f * z;
    }
}

extern "C" void kernel_launch(void* const* d_in, const int* in_sizes, int n_in,
                              void* d_out, int out_size, void* d_ws, size_t ws_size,
                              hipStream_t stream) {
    const float* hs = (const float*)d_in[0];
    const float* Wg = (const float*)d_in[1];
    float* out = (float*)d_out;
    float* ws  = (float*)d_ws;

    const size_t need = (size_t)WS_ACC_FLOATS * sizeof(float)
                      + (size_t)B_ELEMS * 2 * sizeof(__bf16);
    if (ws_size >= need) {
        const __bf16* Bhi = (const __bf16*)(ws + WS_ACC_FLOATS);
        const __bf16* Blo = Bhi + B_ELEMS;
        hipLaunchKernelGGL(prep_kernel, dim3(128), dim3(256), 0, stream, Wg, ws);
        hipLaunchKernelGGL(router_pre_kernel, dim3(NBLK), dim3(256), 0, stream,
                           hs, Bhi, Blo, out, ws);
    } else {
        hipLaunchKernelGGL(zero_ws_kernel, dim3(1), dim3(256), 0, stream, ws);
        hipLaunchKernelGGL(router_fb_kernel, dim3(NBLK), dim3(256), 0, stream,
                           hs, Wg, out, ws);
    }
    hipLaunchKernelGGL(finalize_kernel, dim3(1), dim3(64), 0, stream, ws, out);
}

// Round 6
// 379.472 us; speedup vs baseline: 1.3427x; 1.0386x over previous
//
#include <hip/hip_runtime.h>
#include <hip/hip_bf16.h>

#define NTOK 16384
#define HD   4096
#define NE   64

// PRE path: 32 tokens/block, BK=64 -> 64 k-tiles, 2 blocks/CU
#define TTILE 32
#define NBLK (NTOK / TTILE)   // 512 blocks
#define BK    64
#define NITP  (HD / BK)       // 64 k-tiles (even)

// FB path (round-0 verified): BK=32
#define NIT  (HD / 32)

// LDS row strides (elements)
#define SAB 40   // FB: 32 K + 8 pad
#define SA2 72   // PRE: 64 K + 8 pad -> 144 B rows (16B-aligned; reads 2-way free)
#define SL  68   // float stride for logits tiles

// ws layout (floats): [0,64)=P_sum, [64,128)=counts, [128]=z_sum, pad to 192,
// then Bhi (bf16, NE*HD), then Blo (bf16, NE*HD). ~1.05 MB total.
#define WS_ACC_FLOATS 192
#define B_ELEMS (NE * HD)

typedef __bf16 bf16x8 __attribute__((ext_vector_type(8)));
typedef __bf16 bf16x4 __attribute__((ext_vector_type(4)));
typedef float  f32x4  __attribute__((ext_vector_type(4)));

__device__ __forceinline__ f32x4 mfma16(bf16x8 a, bf16x8 b, f32x4 c) {
    return __builtin_amdgcn_mfma_f32_16x16x32_bf16(a, b, c, 0, 0, 0);
}

__device__ __forceinline__ void cvt_split(float4 v, bf16x4& hi, bf16x4& lo) {
    float x[4] = {v.x, v.y, v.z, v.w};
    #pragma unroll
    for (int e = 0; e < 4; ++e) {
        __bf16 h = (__bf16)x[e];        // RNE
        hi[e] = h;
        lo[e] = (__bf16)(x[e] - (float)h);
    }
}

__device__ __forceinline__ void cvt8(float4 x0, float4 x1, bf16x8& hi, bf16x8& lo) {
    bf16x4 h, l;
    cvt_split(x0, h, l);
    #pragma unroll
    for (int e = 0; e < 4; ++e) { hi[e] = h[e]; lo[e] = l[e]; }
    cvt_split(x1, h, l);
    #pragma unroll
    for (int e = 0; e < 4; ++e) { hi[4 + e] = h[e]; lo[4 + e] = l[e]; }
}

__global__ void zero_ws_kernel(float* ws) {
    int i = threadIdx.x;
    if (i < 129) ws[i] = 0.0f;
}

// One-shot: zero accumulators + convert W_gate fp32 -> bf16 hi/lo in ws.
__global__ __launch_bounds__(256) void prep_kernel(
    const float* __restrict__ Wg, float* __restrict__ ws)
{
    const int tid = threadIdx.x;
    if (blockIdx.x == 0 && tid < 129) ws[tid] = 0.0f;
    __bf16* Bhi = (__bf16*)(ws + WS_ACC_FLOATS);
    __bf16* Blo = Bhi + B_ELEMS;
    const int i = (blockIdx.x * 256 + tid) * 8;
    float4 v0 = *(const float4*)(Wg + i);
    float4 v1 = *(const float4*)(Wg + i + 4);
    bf16x4 h0, l0, h1, l1;
    cvt_split(v0, h0, l0);
    cvt_split(v1, h1, l1);
    *(bf16x4*)(Bhi + i)     = h0;
    *(bf16x4*)(Bhi + i + 4) = h1;
    *(bf16x4*)(Blo + i)     = l0;
    *(bf16x4*)(Blo + i + 4) = l1;
}

// PRE router: r5 champion structure + async pipeline:
//  - raw s_barrier with lgkmcnt(0) only (no vmcnt drain at barrier)
//  - 2-deep register tile prefetch (R0/R1), statically 2x-unrolled
// Global loads for tile t+2 stay in flight across the barrier; the LDS-write
// of tile t+1 gets a compiler-auto counted vmcnt(6). No global stores in the
// loop and LDS is fully fenced by lgkmcnt(0)+barrier -> race-free.
__global__ __launch_bounds__(256, 2) void router_pre_kernel(
    const float* __restrict__ hs,
    const __bf16* __restrict__ Bhi,
    const __bf16* __restrict__ Blo,
    float* __restrict__ out,
    float* __restrict__ ws)
{
    __shared__ __bf16 sAhi[2][TTILE * SA2];  //  9,216 B
    __shared__ __bf16 sAlo[2][TTILE * SA2];  //  9,216 B
    __shared__ __bf16 sBhi[2][NE * SA2];     // 18,432 B
    __shared__ __bf16 sBlo[2][NE * SA2];     // 18,432 B
    __shared__ float  sLog[TTILE * SL];      //  8,704 B
    __shared__ float  sInv[TTILE];
    __shared__ float  sPp[4 * 64];
    __shared__ float  sCnt[64];
    __shared__ float  sZ;
    // total ~65.4 KB -> 2 blocks/CU

    const int tid = threadIdx.x;
    const int t0  = blockIdx.x * TTILE;

    if (tid < 64) sCnt[tid] = 0.0f;
    if (tid == 0) sZ = 0.0f;

    // ---- A staging: 256 threads, each loads 8 floats (2 float4) per tile
    const int rowA = tid >> 3;           // token row 0..31
    const int colA = (tid & 7) * 8;      // k offset (floats) within 64
    const float* gA = hs + (size_t)(t0 + rowA) * HD + colA;
    const int oAw = rowA * SA2 + colA;

    // ---- B staging: 256 threads, each copies 2x16B of Bhi + 2x16B of Blo
    const int eb = tid >> 2;             // expert 0..63
    const int cB = (tid & 3) * 8;        // k offset (elems): cB and cB+32
    const __bf16* gBh = Bhi + (size_t)eb * HD + cB;
    const __bf16* gBl = Blo + (size_t)eb * HD + cB;
    const int oBw = eb * SA2 + cB;

    // ---- wave tile: 16 tok x 32 exp (1x2 MFMA tiles), 4 waves cover 32x64
    const int lane = tid & 63;
    const int wv   = tid >> 6;
    const int wr   = (wv >> 1) * 16;     // token offset: 0 or 16
    const int wc   = (wv & 1) * 32;      // expert offset: 0 or 32
    const int fm   = lane & 15;
    const int fq   = lane >> 4;          // 0..3
    const int fk   = fq * 8;             // k offset within 32-subtile

    f32x4 acc[2];
    acc[0] = (f32x4){0.f, 0.f, 0.f, 0.f};
    acc[1] = (f32x4){0.f, 0.f, 0.f, 0.f};

    // ---- 2-deep register tile buffers (all names static -> stay in VGPRs)
    float4 R0a0, R0a1; bf16x8 R0b0, R0b1, R0b2, R0b3;
    float4 R1a0, R1a1; bf16x8 R1b0, R1b1, R1b2, R1b3;

#define LOADT(R, t)                                                      \
    {                                                                    \
        const int k0 = (t) * BK;                                         \
        R##a0 = *(const float4*)(gA + k0);                               \
        R##a1 = *(const float4*)(gA + k0 + 4);                           \
        R##b0 = *(const bf16x8*)(gBh + k0);                              \
        R##b1 = *(const bf16x8*)(gBh + k0 + 32);                         \
        R##b2 = *(const bf16x8*)(gBl + k0);                              \
        R##b3 = *(const bf16x8*)(gBl + k0 + 32);                         \
    }

#define WRITET(R, buf)                                                   \
    {                                                                    \
        bf16x8 h_, l_;                                                   \
        cvt8(R##a0, R##a1, h_, l_);                                      \
        *(bf16x8*)&sAhi[buf][oAw] = h_;                                  \
        *(bf16x8*)&sAlo[buf][oAw] = l_;                                  \
        *(bf16x8*)&sBhi[buf][oBw]      = R##b0;                          \
        *(bf16x8*)&sBhi[buf][oBw + 32] = R##b1;                          \
        *(bf16x8*)&sBlo[buf][oBw]      = R##b2;                          \
        *(bf16x8*)&sBlo[buf][oBw + 32] = R##b3;                          \
    }

#define COMPUTE(buf)                                                     \
    {                                                                    \
        _Pragma("unroll")                                                \
        for (int kk = 0; kk < 2; ++kk) {                                 \
            const int ao = (wr + fm) * SA2 + kk * 32 + fk;               \
            bf16x8 ahi = *(const bf16x8*)&sAhi[buf][ao];                 \
            bf16x8 alo = *(const bf16x8*)&sAlo[buf][ao];                 \
            const int bo0 = (wc + fm) * SA2 + kk * 32 + fk;              \
            const int bo1 = (wc + 16 + fm) * SA2 + kk * 32 + fk;         \
            bf16x8 bh0 = *(const bf16x8*)&sBhi[buf][bo0];                \
            bf16x8 bh1 = *(const bf16x8*)&sBhi[buf][bo1];                \
            bf16x8 bl0 = *(const bf16x8*)&sBlo[buf][bo0];                \
            bf16x8 bl1 = *(const bf16x8*)&sBlo[buf][bo1];                \
            acc[0] = mfma16(ahi, bh0, acc[0]);                           \
            acc[1] = mfma16(ahi, bh1, acc[1]);                           \
            acc[0] = mfma16(ahi, bl0, acc[0]);                           \
            acc[1] = mfma16(ahi, bl1, acc[1]);                           \
            acc[0] = mfma16(alo, bh0, acc[0]);                           \
            acc[1] = mfma16(alo, bh1, acc[1]);                           \
            acc[0] = mfma16(alo, bl0, acc[0]);                           \
            acc[1] = mfma16(alo, bl1, acc[1]);                           \
        }                                                                \
    }

    // lgkmcnt(0) fences all LDS writes; raw barrier does NOT drain vmcnt,
    // so prefetch loads stay in flight across it. sched_barrier pins order.
#define BAR()                                                            \
    {                                                                    \
        asm volatile("s_waitcnt lgkmcnt(0)" ::: "memory");               \
        __builtin_amdgcn_s_barrier();                                    \
        __builtin_amdgcn_sched_barrier(0);                               \
    }

    // ---- prologue: tiles 0,1 -> regs; tile 0 -> LDS buf0
    LOADT(R0, 0)
    LOADT(R1, 1)
    WRITET(R0, 0)            // auto vmcnt(6): waits R0, R1 stays in flight
    BAR()

    // ---- main loop: 2 k-tiles per trip, 2 barriers per trip
    for (int it = 0; it < NITP; it += 2) {
        const bool m2 = (it + 2) < NITP;
        const bool m3 = (it + 3) < NITP;

        // half A: compute tile it (buf0); stage tile it+1 (buf1); issue it+2
        if (m2) LOADT(R0, it + 2)
        __builtin_amdgcn_sched_barrier(0);   // keep issue above compute
        COMPUTE(0)
        WRITET(R1, 1)        // auto vmcnt(6): waits R1 (loaded 1 iter ago)
        BAR()

        // half B: compute tile it+1 (buf1); stage tile it+2 (buf0); issue it+3
        if (m3) LOADT(R1, it + 3)
        __builtin_amdgcn_sched_barrier(0);
        COMPUTE(1)
        if (m2) WRITET(R0, 0)
        BAR()
    }
#undef LOADT
#undef WRITET
#undef COMPUTE
#undef BAR

    // ---- scatter logits to LDS: C/D layout col=lane&15 (expert), row=fq*4+reg
    #pragma unroll
    for (int j = 0; j < 2; ++j)
        #pragma unroll
        for (int r = 0; r < 4; ++r) {
            const int tokl = wr + fq * 4 + r;
            const int expl = wc + j * 16 + fm;
            sLog[tokl * SL + expl] = acc[j][r];
        }
    __syncthreads();

    // ---- phase 2a: softmax/top-2; 8 lanes per token, 8 experts per lane
    const int g = tid >> 3;       // token 0..31
    const int l = tid & 7;
    float* Lrow = &sLog[g * SL + l * 8];
    float lv[8];
    float m = -3.0e38f;
    #pragma unroll
    for (int c = 0; c < 8; ++c) { lv[c] = Lrow[c]; m = fmaxf(m, lv[c]); }
    m = fmaxf(m, __shfl_xor(m, 1, 64));
    m = fmaxf(m, __shfl_xor(m, 2, 64));
    m = fmaxf(m, __shfl_xor(m, 4, 64));

    float v1 = -3.0e38f, v2 = -3.0e38f; int i1 = 0, i2 = 0;
    float ssum = 0.0f;
    #pragma unroll
    for (int c = 0; c < 8; ++c) {
        const float val = lv[c]; const int idx = l * 8 + c;
        const float ev = __expf(val - m);
        Lrow[c] = ev;               // overwrite logits with exp(l - m)
        ssum += ev;
        if (val > v1) { v2 = v1; i2 = i1; v1 = val; i1 = idx; }
        else if (val > v2) { v2 = val; i2 = idx; }
    }
    ssum += __shfl_xor(ssum, 1, 64);
    ssum += __shfl_xor(ssum, 2, 64);
    ssum += __shfl_xor(ssum, 4, 64);

    #pragma unroll
    for (int s = 1; s <= 4; s <<= 1) {
        const float ov1 = __shfl_xor(v1, s, 64);
        const int   oi1 = __shfl_xor(i1, s, 64);
        const float ov2 = __shfl_xor(v2, s, 64);
        const int   oi2 = __shfl_xor(i2, s, 64);
        float n1, n2; int ni1, ni2;
        const bool ofirst = (ov1 > v1) || (ov1 == v1 && oi1 < i1);
        if (ofirst) {
            n1 = ov1; ni1 = oi1;
            const bool osec = (ov2 > v1) || (ov2 == v1 && oi2 < i1);
            n2 = osec ? ov2 : v1; ni2 = osec ? oi2 : i1;
        } else {
            n1 = v1; ni1 = i1;
            const bool asec = (v2 > ov1) || (v2 == ov1 && i2 < oi1);
            n2 = asec ? v2 : ov1; ni2 = asec ? i2 : oi1;
        }
        v1 = n1; i1 = ni1; v2 = n2; i2 = ni2;
    }

    if (l == 0) {
        const float e1 = __expf(v1 - m), e2 = __expf(v2 - m);
        const float winv = 1.0f / (e1 + e2);
        const int token = t0 + g;
        out[2 * token]     = e1 * winv;
        out[2 * token + 1] = e2 * winv;
        out[2 * NTOK + 2 * token]     = (float)i1;   // indices as f32 (concat promotion)
        out[2 * NTOK + 2 * token + 1] = (float)i2;
        const float lse = m + __logf(ssum);
        atomicAdd(&sZ, lse * lse);
        atomicAdd(&sCnt[i1], 1.0f);
        atomicAdd(&sCnt[i2], 1.0f);
        sInv[g] = 1.0f / ssum;
    }
    __syncthreads();

    // ---- phase 2b: block-local P sums over 32 tokens, then global atomics
    {
        const int e = tid & 63;
        const int q = tid >> 6;
        float part = 0.0f;
        #pragma unroll
        for (int t = 0; t < 8; ++t) {
            const int tok = q * 8 + t;
            part += sLog[tok * SL + e] * sInv[tok];
        }
        sPp[q * 64 + e] = part;
    }
    __syncthreads();
    if (tid < 64) {
        const float ps = sPp[tid] + sPp[64 + tid] + sPp[128 + tid] + sPp[192 + tid];
        atomicAdd(&ws[tid], ps);             // sum of probs per expert
        atomicAdd(&ws[64 + tid], sCnt[tid]); // top-2 counts per expert
    }
    if (tid == 0) atomicAdd(&ws[128], sZ);
}

// Fallback (ws too small for B copies): round-0 verified kernel.
__global__ __launch_bounds__(256) void router_fb_kernel(
    const float* __restrict__ hs,
    const float* __restrict__ Wg,
    float* __restrict__ out,
    float* __restrict__ ws)
{
    __shared__ __bf16 sAhi[2][TTILE * SAB];
    __shared__ __bf16 sAlo[2][TTILE * SAB];
    __shared__ __bf16 sBhi[2][NE * SAB];
    __shared__ __bf16 sBlo[2][NE * SAB];
    __shared__ float  sLog[TTILE * SL];
    __shared__ float  sInv[TTILE];
    __shared__ float  sPp[4 * 64];
    __shared__ float  sCnt[64];
    __shared__ float  sZ;

    const int tid = threadIdx.x;
    const int t0  = blockIdx.x * TTILE;

    if (tid < 64) sCnt[tid] = 0.0f;
    if (tid == 0) sZ = 0.0f;

    const int r1 = tid >> 3;
    const int c4 = (tid & 7) * 4;
    const float* gA = hs + (size_t)(t0 + r1) * HD + c4;
    const float* gB = Wg + (size_t)r1 * HD + c4;
    const int oA  = r1 * SAB + c4;
    const int oB1 = r1 * SAB + c4;
    const int oB2 = (r1 + 32) * SAB + c4;

    const int lane = tid & 63;
    const int wv   = tid >> 6;
    const int wr   = (wv >> 1) * 16;
    const int wc   = (wv & 1) * 32;
    const int fm   = lane & 15;
    const int fq   = lane >> 4;
    const int fk   = fq * 8;

    f32x4 acc[2];
    acc[0] = (f32x4){0.f, 0.f, 0.f, 0.f};
    acc[1] = (f32x4){0.f, 0.f, 0.f, 0.f};

    {
        float4 a0 = *(const float4*)(gA);
        float4 b0 = *(const float4*)(gB);
        float4 b1 = *(const float4*)(gB + 32 * HD);
        bf16x4 h, l;
        cvt_split(a0, h, l); *(bf16x4*)&sAhi[0][oA]  = h; *(bf16x4*)&sAlo[0][oA]  = l;
        cvt_split(b0, h, l); *(bf16x4*)&sBhi[0][oB1] = h; *(bf16x4*)&sBlo[0][oB1] = l;
        cvt_split(b1, h, l); *(bf16x4*)&sBhi[0][oB2] = h; *(bf16x4*)&sBlo[0][oB2] = l;
    }
    __syncthreads();

    for (int it = 0; it < NIT; ++it) {
        const int cur = it & 1;
        const bool more = (it + 1) < NIT;
        float4 na0, nb0, nb1;
        if (more) {
            const int k0 = (it + 1) * 32;
            na0 = *(const float4*)(gA + k0);
            nb0 = *(const float4*)(gB + k0);
            nb1 = *(const float4*)(gB + 32 * HD + k0);
        }

        bf16x8 ahi, alo, bhi[2], blo[2];
        {
            const int aoff = (wr + fm) * SAB + fk;
            ahi = *(const bf16x8*)&sAhi[cur][aoff];
            alo = *(const bf16x8*)&sAlo[cur][aoff];
        }
        #pragma unroll
        for (int j = 0; j < 2; ++j) {
            const int boff = (wc + j * 16 + fm) * SAB + fk;
            bhi[j] = *(const bf16x8*)&sBhi[cur][boff];
            blo[j] = *(const bf16x8*)&sBlo[cur][boff];
        }
        #pragma unroll
        for (int j = 0; j < 2; ++j) {
            acc[j] = mfma16(ahi, bhi[j], acc[j]);
            acc[j] = mfma16(ahi, blo[j], acc[j]);
            acc[j] = mfma16(alo, bhi[j], acc[j]);
            acc[j] = mfma16(alo, blo[j], acc[j]);
        }

        if (more) {
            const int nb = cur ^ 1;
            bf16x4 h, l;
            cvt_split(na0, h, l); *(bf16x4*)&sAhi[nb][oA]  = h; *(bf16x4*)&sAlo[nb][oA]  = l;
            cvt_split(nb0, h, l); *(bf16x4*)&sBhi[nb][oB1] = h; *(bf16x4*)&sBlo[nb][oB1] = l;
            cvt_split(nb1, h, l); *(bf16x4*)&sBhi[nb][oB2] = h; *(bf16x4*)&sBlo[nb][oB2] = l;
        }
        __syncthreads();
    }

    #pragma unroll
    for (int j = 0; j < 2; ++j)
        #pragma unroll
        for (int r = 0; r < 4; ++r) {
            const int tokl = wr + fq * 4 + r;
            const int expl = wc + j * 16 + fm;
            sLog[tokl * SL + expl] = acc[j][r];
        }
    __syncthreads();

    const int g = tid >> 3;
    const int l = tid & 7;
    float* Lrow = &sLog[g * SL + l * 8];
    float lv[8];
    float m = -3.0e38f;
    #pragma unroll
    for (int c = 0; c < 8; ++c) { lv[c] = Lrow[c]; m = fmaxf(m, lv[c]); }
    m = fmaxf(m, __shfl_xor(m, 1, 64));
    m = fmaxf(m, __shfl_xor(m, 2, 64));
    m = fmaxf(m, __shfl_xor(m, 4, 64));

    float v1 = -3.0e38f, v2 = -3.0e38f; int i1 = 0, i2 = 0;
    float ssum = 0.0f;
    #pragma unroll
    for (int c = 0; c < 8; ++c) {
        const float val = lv[c]; const int idx = l * 8 + c;
        const float ev = __expf(val - m);
        Lrow[c] = ev;
        ssum += ev;
        if (val > v1) { v2 = v1; i2 = i1; v1 = val; i1 = idx; }
        else if (val > v2) { v2 = val; i2 = idx; }
    }
    ssum += __shfl_xor(ssum, 1, 64);
    ssum += __shfl_xor(ssum, 2, 64);
    ssum += __shfl_xor(ssum, 4, 64);

    #pragma unroll
    for (int s = 1; s <= 4; s <<= 1) {
        const float ov1 = __shfl_xor(v1, s, 64);
        const int   oi1 = __shfl_xor(i1, s, 64);
        const float ov2 = __shfl_xor(v2, s, 64);
        const int   oi2 = __shfl_xor(i2, s, 64);
        float n1, n2; int ni1, ni2;
        const bool ofirst = (ov1 > v1) || (ov1 == v1 && oi1 < i1);
        if (ofirst) {
            n1 = ov1; ni1 = oi1;
            const bool osec = (ov2 > v1) || (ov2 == v1 && oi2 < i1);
            n2 = osec ? ov2 : v1; ni2 = osec ? oi2 : i1;
        } else {
            n1 = v1; ni1 = i1;
            const bool asec = (v2 > ov1) || (v2 == ov1 && i2 < oi1);
            n2 = asec ? v2 : ov1; ni2 = asec ? i2 : oi1;
        }
        v1 = n1; i1 = ni1; v2 = n2; i2 = ni2;
    }

    if (l == 0) {
        const float e1 = __expf(v1 - m), e2 = __expf(v2 - m);
        const float winv = 1.0f / (e1 + e2);
        const int token = t0 + g;
        out[2 * token]     = e1 * winv;
        out[2 * token + 1] = e2 * winv;
        out[2 * NTOK + 2 * token]     = (float)i1;
        out[2 * NTOK + 2 * token + 1] = (float)i2;
        const float lse = m + __logf(ssum);
        atomicAdd(&sZ, lse * lse);
        atomicAdd(&sCnt[i1], 1.0f);
        atomicAdd(&sCnt[i2], 1.0f);
        sInv[g] = 1.0f / ssum;
    }
    __syncthreads();

    {
        const int e = tid & 63;
        const int q = tid >> 6;
        float part = 0.0f;
        #pragma unroll
        for (int t = 0; t < 8; ++t) {
            const int tok = q * 8 + t;
            part += sLog[tok * SL + e] * sInv[tok];
        }
        sPp[q * 64 + e] = part;
    }
    __syncthreads();
    if (tid < 64) {
        const float ps = sPp[tid] + sPp[64 + tid] + sPp[128 + tid] + sPp[192 + tid];
        atomicAdd(&ws[tid], ps);
        atomicAdd(&ws[64 + tid], sCnt[tid]);
    }
    if (tid == 0) atomicAdd(&ws[128], sZ);
}

__global__ void finalize_kernel(const float* __restrict__ ws, float* __restrict__ out) {
    const int e = threadIdx.x;   // 64 threads, one wave
    const float P = ws[e] * (1.0f / NTOK);
    const float f = ws[64 + e] * (1.0f / (NTOK * 2));
    float term = f * P;
    #pragma unroll
    for (int s = 32; s >= 1; s >>= 1) term += __shfl_xor(term, s, 64);
    if (e == 0) {
        const float lb = 64.0f * term;
        const float z  = ws[128] * (1.0f / NTOK);
        out[4 * NTOK] = 0.001f * lb + 0.001f * z;
    }
}

extern "C" void kernel_launch(void* const* d_in, const int* in_sizes, int n_in,
                              void* d_out, int out_size, void* d_ws, size_t ws_size,
                              hipStream_t stream) {
    const float* hs = (const float*)d_in[0];
    const float* Wg = (const float*)d_in[1];
    float* out = (float*)d_out;
    float* ws  = (float*)d_ws;

    const size_t need = (size_t)WS_ACC_FLOATS * sizeof(float)
                      + (size_t)B_ELEMS * 2 * sizeof(__bf16);
    if (ws_size >= need) {
        const __bf16* Bhi = (const __bf16*)(ws + WS_ACC_FLOATS);
        const __bf16* Blo = Bhi + B_ELEMS;
        hipLaunchKernelGGL(prep_kernel, dim3(128), dim3(256), 0, stream, Wg, ws);
        hipLaunchKernelGGL(router_pre_kernel, dim3(NBLK), dim3(256), 0, stream,
                           hs, Bhi, Blo, out, ws);
    } else {
        hipLaunchKernelGGL(zero_ws_kernel, dim3(1), dim3(256), 0, stream, ws);
        hipLaunchKernelGGL(router_fb_kernel, dim3(NBLK), dim3(256), 0, stream,
                           hs, Wg, out, ws);
    }
    hipLaunchKernelGGL(finalize_kernel, dim3(1), dim3(64), 0, stream, ws, out);
}